// Round 1
// baseline (1755.102 us; speedup 1.0000x reference)
//
#include <hip/hip_runtime.h>
#include <math.h>

#define FDIM 32
#define NBASIS 8

constexpr float RCUT_C = 20.0f;
constexpr float PI_F = 3.14159265358979323846f;
constexpr float EV2KJ_C = 96.4853f;
constexpr float NM2A_C = 10.0f;

__device__ __forceinline__ float sigmoidf_(float z) { return 1.0f / (1.0f + __expf(-z)); }

// ---------------- edge forward: accumulate s (N*32) and v (N*96) ----------------
__global__ __launch_bounds__(256) void edge_fwd(
    const float* __restrict__ pos, const int* __restrict__ types,
    const int* __restrict__ eidx,
    const float* __restrict__ Wr1, const float* __restrict__ br1,
    const float* __restrict__ Wr2, const float* __restrict__ temb,
    float* __restrict__ s_acc, float* __restrict__ v_acc, int E)
{
    __shared__ float sW1[NBASIS * FDIM], sb1[FDIM], sW2[FDIM * 2 * FDIM], sTE[3 * FDIM];
    for (int i = threadIdx.x; i < NBASIS * FDIM; i += 256) sW1[i] = Wr1[i];
    for (int i = threadIdx.x; i < FDIM; i += 256) sb1[i] = br1[i];
    for (int i = threadIdx.x; i < FDIM * 2 * FDIM; i += 256) sW2[i] = Wr2[i];
    for (int i = threadIdx.x; i < 3 * FDIM; i += 256) sTE[i] = temb[i];
    __syncthreads();

    const int lane = threadIdx.x & 31;
    int e = blockIdx.x * 8 + (threadIdx.x >> 5);
    const bool valid = (e < E);
    if (!valid) e = 0;
    const int src = eidx[e], dst = eidx[E + e];

    float rx = (pos[dst * 3 + 0] - pos[src * 3 + 0]) * NM2A_C;
    float ry = (pos[dst * 3 + 1] - pos[src * 3 + 1]) * NM2A_C;
    float rz = (pos[dst * 3 + 2] - pos[src * 3 + 2]) * NM2A_C;
    float r2 = rx * rx + ry * ry + rz * rz + 1e-12f;
    float r = sqrtf(r2);
    float rinv = 1.0f / r;
    float x = r * (1.0f / RCUT_C);
    float x2 = x * x, x4 = x2 * x2, x6 = x4 * x2, x7 = x6 * x, x8 = x6 * x2;
    float env = (x < 1.0f) ? (1.0f - 28.0f * x6 + 48.0f * x7 - 21.0f * x8) : 0.0f;

    float th = PI_F * x, s1, c1;
    __sincosf(th, &s1, &c1);
    float sp = 0.0f, sn = s1;           // sin(n*th) recurrence
    float z = sb1[lane];
    #pragma unroll
    for (int n = 0; n < NBASIS; n++) {
        float basis = sn * rinv;
        z += basis * sW1[n * FDIM + lane];
        float snx = 2.0f * c1 * sn - sp; sp = sn; sn = snx;
    }
    float sg = sigmoidf_(z);
    float q = z * sg;

    float rw0 = 0.0f, rw1 = 0.0f;
    #pragma unroll
    for (int f = 0; f < FDIM; f++) {
        float qv = __shfl(q, f, 32);
        rw0 += qv * sW2[f * 64 + lane];
        rw1 += qv * sW2[f * 64 + 32 + lane];
    }
    float hs = sTE[types[src] * FDIM + lane];
    float w0 = rw0 * env, w1 = rw1 * env;

    if (valid) {
        unsafeAtomicAdd(&s_acc[(size_t)dst * FDIM + lane], hs * w0);
        float hw1 = hs * w1;
        unsafeAtomicAdd(&v_acc[(size_t)dst * 96 + lane * 3 + 0], hw1 * rx * rinv);
        unsafeAtomicAdd(&v_acc[(size_t)dst * 96 + lane * 3 + 1], hw1 * ry * rinv);
        unsafeAtomicAdd(&v_acc[(size_t)dst * 96 + lane * 3 + 2], hw1 * rz * rinv);
    }
}

// -------- atom MLP: energy partials + g_s/g_v (written in-place over s/v) --------
__global__ __launch_bounds__(256) void atom_mlp(
    const int* __restrict__ types, const float* __restrict__ temb,
    const float* __restrict__ Wself, const float* __restrict__ Wo1,
    const float* __restrict__ bo1, const float* __restrict__ Wo2,
    float* __restrict__ s_acc, float* __restrict__ v_acc,
    float* __restrict__ e_partial, int N)
{
    __shared__ float sWs[FDIM * FDIM], sWsT[FDIM * FDIM];
    __shared__ float sWo1[2 * FDIM * FDIM], sWo1T[2 * FDIM * FDIM];
    __shared__ float sb[FDIM], sW2o[FDIM], sTE[3 * FDIM];
    __shared__ float gred[8];
    for (int i = threadIdx.x; i < FDIM * FDIM; i += 256) {
        sWs[i] = Wself[i];
        sWsT[i] = Wself[(i & 31) * FDIM + (i >> 5)];       // [k*32+f] = Wself[f][k]
    }
    for (int i = threadIdx.x; i < 2 * FDIM * FDIM; i += 256) {
        sWo1[i] = Wo1[i];
        sWo1T[i] = Wo1[(i & 63) * FDIM + (i >> 6)];        // [k*64+j] = Wo1[j][k]
    }
    for (int i = threadIdx.x; i < FDIM; i += 256) { sb[i] = bo1[i]; sW2o[i] = Wo2[i]; }
    for (int i = threadIdx.x; i < 3 * FDIM; i += 256) sTE[i] = temb[i];
    __syncthreads();

    const int lane = threadIdx.x & 31;
    const int g = threadIdx.x >> 5;
    int a = blockIdx.x * 8 + g;
    const bool valid = (a < N);
    if (!valid) a = 0;

    float sv = s_acc[(size_t)a * FDIM + lane];
    float vx = v_acc[(size_t)a * 96 + lane * 3 + 0];
    float vy = v_acc[(size_t)a * 96 + lane * 3 + 1];
    float vz = v_acc[(size_t)a * 96 + lane * 3 + 2];
    float h = sTE[types[a] * FDIM + lane];
    float vn = sqrtf(vx * vx + vy * vy + vz * vz + 1e-12f);

    float row = h;
    #pragma unroll
    for (int f = 0; f < FDIM; f++) {
        float t = __shfl(sv, f, 32);
        row += t * sWs[f * FDIM + lane];
    }
    float u = sb[lane];
    #pragma unroll
    for (int j = 0; j < FDIM; j++) {
        float rv = __shfl(row, j, 32);
        float vv = __shfl(vn, j, 32);
        u += rv * sWo1[j * FDIM + lane] + vv * sWo1[(j + FDIM) * FDIM + lane];
    }
    float sg = sigmoidf_(u);
    float au = u * sg;
    float pa = valid ? au * sW2o[lane] : 0.0f;
    #pragma unroll
    for (int m = 16; m; m >>= 1) pa += __shfl_xor(pa, m, 32);
    if (lane == 0) gred[g] = pa;

    // backward
    float gu = sW2o[lane] * (sg * (1.0f + u * (1.0f - sg)));
    float gfr = 0.0f, gfv = 0.0f;
    #pragma unroll
    for (int k = 0; k < FDIM; k++) {
        float gv_ = __shfl(gu, k, 32);
        gfr += gv_ * sWo1T[k * 64 + lane];
        gfv += gv_ * sWo1T[k * 64 + 32 + lane];
    }
    float gs = 0.0f;
    #pragma unroll
    for (int k = 0; k < FDIM; k++) {
        float gr = __shfl(gfr, k, 32);
        gs += gr * sWsT[k * FDIM + lane];
    }
    __syncthreads();
    if (valid) {
        s_acc[(size_t)a * FDIM + lane] = gs;
        float sc = gfv / vn;
        v_acc[(size_t)a * 96 + lane * 3 + 0] = sc * vx;
        v_acc[(size_t)a * 96 + lane * 3 + 1] = sc * vy;
        v_acc[(size_t)a * 96 + lane * 3 + 2] = sc * vz;
    }
    if (threadIdx.x == 0) {
        float t = 0.0f;
        #pragma unroll
        for (int i = 0; i < 8; i++) t += gred[i];
        e_partial[blockIdx.x] = t;
    }
}

// ---------------- edge backward: recompute fwd, scatter forces ----------------
__global__ __launch_bounds__(256) void edge_bwd(
    const float* __restrict__ pos, const int* __restrict__ types,
    const int* __restrict__ eidx,
    const float* __restrict__ Wr1, const float* __restrict__ br1,
    const float* __restrict__ Wr2, const float* __restrict__ temb,
    const float* __restrict__ g_s, const float* __restrict__ g_v,
    float* __restrict__ forces, int E)
{
    __shared__ float sW1[NBASIS * FDIM], sb1[FDIM], sW2[2048], sW2T[2048], sTE[96];
    for (int i = threadIdx.x; i < NBASIS * FDIM; i += 256) sW1[i] = Wr1[i];
    for (int i = threadIdx.x; i < FDIM; i += 256) sb1[i] = br1[i];
    for (int i = threadIdx.x; i < 2048; i += 256) {
        sW2[i] = Wr2[i];
        sW2T[i] = Wr2[(i & 31) * 64 + (i >> 5)];           // [j*32+f] = Wr2[f][j]
    }
    for (int i = threadIdx.x; i < 96; i += 256) sTE[i] = temb[i];
    __syncthreads();

    const int lane = threadIdx.x & 31;
    int e = blockIdx.x * 8 + (threadIdx.x >> 5);
    const bool valid = (e < E);
    if (!valid) e = 0;
    const int src = eidx[e], dst = eidx[E + e];

    float rx = (pos[dst * 3 + 0] - pos[src * 3 + 0]) * NM2A_C;
    float ry = (pos[dst * 3 + 1] - pos[src * 3 + 1]) * NM2A_C;
    float rz = (pos[dst * 3 + 2] - pos[src * 3 + 2]) * NM2A_C;
    float r2 = rx * rx + ry * ry + rz * rz + 1e-12f;
    float r = sqrtf(r2);
    float rinv = 1.0f / r;
    float x = r * (1.0f / RCUT_C);
    float x2 = x * x, x4 = x2 * x2, x5 = x4 * x, x6 = x4 * x2, x7 = x6 * x, x8 = x6 * x2;
    float env = (x < 1.0f) ? (1.0f - 28.0f * x6 + 48.0f * x7 - 21.0f * x8) : 0.0f;
    float denv = (x < 1.0f) ? (-168.0f * x5 + 336.0f * x6 - 168.0f * x7) * (1.0f / RCUT_C) : 0.0f;

    float th = PI_F * x, s1, c1;
    __sincosf(th, &s1, &c1);
    float sp = 0.0f, sn = s1;
    float cp = 1.0f, cn = c1;
    float z = sb1[lane];
    float tacc = 0.0f;  // sum_n W1[n][lane] * d(basis_n)/dr
    #pragma unroll
    for (int n = 0; n < NBASIS; n++) {
        float basis = sn * rinv;
        float wv = sW1[n * FDIM + lane];
        z += basis * wv;
        float dbdr = (PI_F * (float)(n + 1) * (1.0f / RCUT_C)) * cn * rinv - basis * rinv;
        tacc += dbdr * wv;
        float snx = 2.0f * c1 * sn - sp; sp = sn; sn = snx;
        float cnx = 2.0f * c1 * cn - cp; cp = cn; cn = cnx;
    }
    float sg = sigmoidf_(z);
    float q = z * sg;

    float rw0 = 0.0f, rw1 = 0.0f;
    #pragma unroll
    for (int f = 0; f < FDIM; f++) {
        float qv = __shfl(q, f, 32);
        rw0 += qv * sW2[f * 64 + lane];
        rw1 += qv * sW2[f * 64 + 32 + lane];
    }
    float hs = sTE[types[src] * FDIM + lane];
    float w1 = rw1 * env;

    float gm0 = g_s[(size_t)dst * FDIM + lane];
    float gm1x = g_v[(size_t)dst * 96 + lane * 3 + 0];
    float gm1y = g_v[(size_t)dst * 96 + lane * 3 + 1];
    float gm1z = g_v[(size_t)dst * 96 + lane * 3 + 2];

    float rhx = rx * rinv, rhy = ry * rinv, rhz = rz * rinv;
    float gw0 = hs * gm0;
    float gw1 = hs * (gm1x * rhx + gm1y * rhy + gm1z * rhz);
    float hw1 = hs * w1;
    float grx = hw1 * gm1x, gry = hw1 * gm1y, grz = hw1 * gm1z;  // g_rhat partials
    float genv = gw0 * rw0 + gw1 * rw1;                           // g_env partial
    float gr0 = gw0 * env, gr1 = gw1 * env;                       // g wrt rw_raw

    float gq = 0.0f;
    #pragma unroll
    for (int j = 0; j < FDIM; j++) {
        float a0 = __shfl(gr0, j, 32);
        float a1 = __shfl(gr1, j, 32);
        gq += a0 * sW2T[j * 32 + lane] + a1 * sW2T[(j + 32) * 32 + lane];
    }
    float gzv = gq * (sg * (1.0f + z * (1.0f - sg)));
    float grp = gzv * tacc;                                       // g_r partial (basis path)

    #pragma unroll
    for (int m = 16; m; m >>= 1) {
        grx += __shfl_xor(grx, m, 32);
        gry += __shfl_xor(gry, m, 32);
        grz += __shfl_xor(grz, m, 32);
        genv += __shfl_xor(genv, m, 32);
        grp += __shfl_xor(grp, m, 32);
    }

    float g_r = grp + genv * denv;
    float dotg = grx * rhx + gry * rhy + grz * rhz;
    float gex = g_r * rhx + (grx - dotg * rhx) * rinv;
    float gey = g_r * rhy + (gry - dotg * rhy) * rinv;
    float gez = g_r * rhz + (grz - dotg * rhz) * rinv;

    const float SC = EV2KJ_C * NM2A_C;  // 964.853
    if (valid && lane < 6) {
        int c = (lane < 3) ? lane : lane - 3;
        float comp = (c == 0) ? gex : ((c == 1) ? gey : gez);
        if (lane < 3) unsafeAtomicAdd(&forces[(size_t)dst * 3 + c], -SC * comp);
        else          unsafeAtomicAdd(&forces[(size_t)src * 3 + c],  SC * comp);
    }
}

// ---------------- reductions & correction ----------------
__global__ __launch_bounds__(256) void reduce_energy(
    const float* __restrict__ e_partial, int n, float* __restrict__ out)
{
    __shared__ float red[256];
    float s = 0.0f;
    for (int i = threadIdx.x; i < n; i += 256) s += e_partial[i];
    red[threadIdx.x] = s;
    __syncthreads();
    for (int k = 128; k; k >>= 1) {
        if (threadIdx.x < k) red[threadIdx.x] += red[threadIdx.x + k];
        __syncthreads();
    }
    if (threadIdx.x == 0) out[0] = red[0] * EV2KJ_C;
}

__global__ __launch_bounds__(256) void reduce_net(
    const float* __restrict__ f, const float* __restrict__ masses,
    float* __restrict__ accum, int N)
{
    float nx = 0, ny = 0, nz = 0, ms = 0;
    for (int i = blockIdx.x * 256 + threadIdx.x; i < N; i += gridDim.x * 256) {
        nx += f[i * 3 + 0]; ny += f[i * 3 + 1]; nz += f[i * 3 + 2]; ms += masses[i];
    }
    #pragma unroll
    for (int m = 32; m; m >>= 1) {
        nx += __shfl_xor(nx, m, 64);
        ny += __shfl_xor(ny, m, 64);
        nz += __shfl_xor(nz, m, 64);
        ms += __shfl_xor(ms, m, 64);
    }
    __shared__ float red[4][4];
    int w = threadIdx.x >> 6;
    if ((threadIdx.x & 63) == 0) { red[w][0] = nx; red[w][1] = ny; red[w][2] = nz; red[w][3] = ms; }
    __syncthreads();
    if (threadIdx.x == 0) {
        float a0 = 0, a1 = 0, a2 = 0, a3 = 0;
        for (int i = 0; i < 4; i++) { a0 += red[i][0]; a1 += red[i][1]; a2 += red[i][2]; a3 += red[i][3]; }
        unsafeAtomicAdd(accum + 0, a0);
        unsafeAtomicAdd(accum + 1, a1);
        unsafeAtomicAdd(accum + 2, a2);
        unsafeAtomicAdd(accum + 3, a3);
    }
}

__global__ __launch_bounds__(256) void correct_forces(
    float* __restrict__ f, const float* __restrict__ masses,
    const float* __restrict__ accum, int N)
{
    int i = blockIdx.x * 256 + threadIdx.x;
    if (i < N) {
        float c = masses[i] / accum[3];
        f[i * 3 + 0] -= c * accum[0];
        f[i * 3 + 1] -= c * accum[1];
        f[i * 3 + 2] -= c * accum[2];
    }
}

extern "C" void kernel_launch(void* const* d_in, const int* in_sizes, int n_in,
                              void* d_out, int out_size, void* d_ws, size_t ws_size,
                              hipStream_t stream)
{
    (void)n_in; (void)ws_size;
    const float* pos    = (const float*)d_in[0];
    const float* masses = (const float*)d_in[1];
    const float* temb   = (const float*)d_in[2];
    const float* Wr1    = (const float*)d_in[3];
    const float* br1    = (const float*)d_in[4];
    const float* Wr2    = (const float*)d_in[5];
    const float* Wself  = (const float*)d_in[6];
    const float* Wo1    = (const float*)d_in[7];
    const float* bo1    = (const float*)d_in[8];
    const float* Wo2    = (const float*)d_in[9];
    const int* types    = (const int*)d_in[10];
    const int* eidx     = (const int*)d_in[11];
    const int N = in_sizes[1];
    const int E = in_sizes[11] / 2;

    float* out = (float*)d_out;
    float* forces = out + 1;

    float* ws = (float*)d_ws;
    float* s_acc = ws;                              // N*32
    float* v_acc = s_acc + (size_t)N * FDIM;        // N*96
    int nAtomBlocks = (N + 7) / 8;
    float* e_partial = v_acc + (size_t)N * 96;      // nAtomBlocks
    float* accum = e_partial + nAtomBlocks;         // 4

    hipMemsetAsync(d_out, 0, (size_t)out_size * sizeof(float), stream);
    hipMemsetAsync(s_acc, 0, (size_t)N * 128 * sizeof(float), stream);
    hipMemsetAsync(accum, 0, 4 * sizeof(float), stream);

    int nEdgeBlocks = (E + 7) / 8;
    edge_fwd<<<nEdgeBlocks, 256, 0, stream>>>(pos, types, eidx, Wr1, br1, Wr2, temb,
                                              s_acc, v_acc, E);
    atom_mlp<<<nAtomBlocks, 256, 0, stream>>>(types, temb, Wself, Wo1, bo1, Wo2,
                                              s_acc, v_acc, e_partial, N);
    reduce_energy<<<1, 256, 0, stream>>>(e_partial, nAtomBlocks, out);
    edge_bwd<<<nEdgeBlocks, 256, 0, stream>>>(pos, types, eidx, Wr1, br1, Wr2, temb,
                                              s_acc, v_acc, forces, E);
    reduce_net<<<64, 256, 0, stream>>>(forces, masses, accum, N);
    correct_forces<<<(N + 255) / 256, 256, 0, stream>>>(forces, masses, accum, N);
}